// Round 11
// baseline (65.424 us; speedup 1.0000x reference)
//
#include <hip/hip_runtime.h>
#include <hip/hip_fp16.h>

#define N_NODES 100000
#define N_EDGES 600000
#define DIM 128
#define HID 64
#define NCHUNK 1563          // ceil(100000 / 64)

typedef __attribute__((ext_vector_type(8))) _Float16 half8;
typedef __attribute__((ext_vector_type(4))) _Float16 half4v;
typedef __attribute__((ext_vector_type(4))) float floatx4;
typedef __attribute__((ext_vector_type(4))) unsigned int uint4v;

// direct global -> LDS, 16 B per lane (dest must be lane-linear!)
__device__ __forceinline__ void gload_lds16(const void* g, void* l) {
    __builtin_amdgcn_global_load_lds(
        (const __attribute__((address_space(1))) void*)g,
        (__attribute__((address_space(3))) void*)l, 16, 0, 0);
}

// ---------------------------------------------------------------------------
// Kernel 0: W1T[c][k] (f16, [128][128]) = c<64 ? W1[k][c] : W1[128+k][c-64]
// ---------------------------------------------------------------------------
__global__ __launch_bounds__(256) void prep_W(
    const float* __restrict__ W1, __half* __restrict__ W1T)
{
    const int o = (int)(blockIdx.x * blockDim.x + threadIdx.x) * 2;
    if (o >= 128 * 128) return;
    const int c = o >> 7, k = o & 127;
    float w0, w1;
    if (c < HID) { w0 = W1[k * HID + c];               w1 = W1[(k + 1) * HID + c]; }
    else         { w0 = W1[(DIM + k) * HID + c - HID]; w1 = W1[(DIM + k + 1) * HID + c - HID]; }
    W1T[o]     = __float2half(w0);
    W1T[o + 1] = __float2half(w1);
}

// ---------------------------------------------------------------------------
// Kernel 1: ONE-SHOT blocks, column-split passes.
// Block = 64-row chunk: stage once into 32KB LDS (gload_lds, XOR-swizzled
// source), then two passes over cols (0-63, 64-127) with wf[4][4] pinned in
// 32 VGPRs each. ~80 VGPR + 32KB LDS -> 5 blocks/CU, 20 waves/CU; latency
// hidden by inter-block overlap, not intra-block pipelining.
// Output P layout (permuted, as R5): hidden h=(2m+t)*16+4q+i at byte
// offset m*64 + q*16 + (t*4+i)*2 within the node's 256-B row.
// ---------------------------------------------------------------------------
__global__ __launch_bounds__(256, 5) void precompute_P(
    const float* __restrict__ node_emb,
    const __half* __restrict__ W1T,
    const float* __restrict__ b1,
    __half* __restrict__ P)
{
    __shared__ char Abuf[64 * 512];          // 32 KB, single buffer

    const int tid  = threadIdx.x;
    const int w    = tid >> 6;
    const int lane = tid & 63;
    const int lr   = lane & 15;
    const int q    = lane >> 4;
    const int c    = (int)blockIdx.x;

    const char* nb = (const char*)node_emb;
    const int r8   = tid >> 5;
    const int in16 = (tid & 31) << 4;

    // stage 64 rows x 512 B (8 rounds x 256 lanes x 16 B), source XOR-swizzled
#pragma unroll
    for (int r = 0; r < 8; r++) {
        int row_in = r * 8 + r8;
        int grow = c * 64 + row_in;
        if (grow >= N_NODES) grow = N_NODES - 1;
        const size_t src = (size_t)grow * 512 + (size_t)(in16 ^ ((row_in & 7) << 4));
        gload_lds16(nb + src, &Abuf[r * 4096 + tid * 16]);
    }

    const int rb   = w * 16 + lr;            // row within chunk
    const int sw   = (lr & 7) << 4;          // rb&7 == lr&7
    const int grow = c * 64 + rb;
    char* prow = (char*)P + (size_t)grow * 256;
    const bool wr = (grow < N_NODES);

#pragma unroll 1
    for (int h = 0; h < 2; h++) {            // column half: cols h*64..h*64+63
        // wf for this half -> 32 VGPRs (issued before the vmcnt on h=0,
        // so they overlap the staging loads)
        half8 wf[4][4];
#pragma unroll
        for (int nt = 0; nt < 4; nt++)
#pragma unroll
            for (int ks = 0; ks < 4; ks++)
                wf[nt][ks] = *(const half8*)(W1T + (size_t)(h * 64 + nt * 16 + lr) * 128 + ks * 32 + q * 8);
        // PIN: block rematerialization of wf inside the MFMA loop
#pragma unroll
        for (int nt = 0; nt < 4; nt++)
#pragma unroll
            for (int ks = 0; ks < 4; ks++) {
                uint4v t = __builtin_bit_cast(uint4v, wf[nt][ks]);
                asm volatile("" : "+v"(t));
                wf[nt][ks] = __builtin_bit_cast(half8, t);
            }

        if (h == 0) {
            asm volatile("s_waitcnt vmcnt(0)" ::: "memory");   // LDS staged
            __builtin_amdgcn_s_barrier();
        }

        floatx4 acc[4];
#pragma unroll
        for (int nt = 0; nt < 4; nt++) acc[nt] = (floatx4){0.f, 0.f, 0.f, 0.f};

#pragma unroll
        for (int ks = 0; ks < 4; ks++) {
            const int cb = ks * 128 + q * 32;
            const float4 x0 = *(const float4*)(Abuf + rb * 512 + ((cb)      ^ sw));
            const float4 x1 = *(const float4*)(Abuf + rb * 512 + ((cb + 16) ^ sw));
            half8 af;
            af[0] = (_Float16)x0.x; af[1] = (_Float16)x0.y;
            af[2] = (_Float16)x0.z; af[3] = (_Float16)x0.w;
            af[4] = (_Float16)x1.x; af[5] = (_Float16)x1.y;
            af[6] = (_Float16)x1.z; af[7] = (_Float16)x1.w;
#pragma unroll
            for (int nt = 0; nt < 4; nt++)
                acc[nt] = __builtin_amdgcn_mfma_f32_16x16x32_f16(wf[nt][ks], af, acc[nt], 0, 0, 0);
        }

        if (wr) {
#pragma unroll
            for (int mm = 0; mm < 2; mm++) {
                float va0 = acc[2 * mm][0], va1 = acc[2 * mm][1],
                      va2 = acc[2 * mm][2], va3 = acc[2 * mm][3];
                float vb0 = acc[2 * mm + 1][0], vb1 = acc[2 * mm + 1][1],
                      vb2 = acc[2 * mm + 1][2], vb3 = acc[2 * mm + 1][3];
                if (h == 0) {                 // bias only on hidden cols 0..63
                    const float4 ba = *(const float4*)(b1 + (2 * mm) * 16 + q * 4);
                    const float4 bb = *(const float4*)(b1 + (2 * mm + 1) * 16 + q * 4);
                    va0 += ba.x; va1 += ba.y; va2 += ba.z; va3 += ba.w;
                    vb0 += bb.x; vb1 += bb.y; vb2 += bb.z; vb3 += bb.w;
                }
                half8 hh;
                hh[0] = (_Float16)va0; hh[1] = (_Float16)va1;
                hh[2] = (_Float16)va2; hh[3] = (_Float16)va3;
                hh[4] = (_Float16)vb0; hh[5] = (_Float16)vb1;
                hh[6] = (_Float16)vb2; hh[7] = (_Float16)vb3;
                const int m = 2 * h + mm;
                *(half8*)(prow + m * 64 + q * 16) = hh;
            }
        }
        __builtin_amdgcn_sched_barrier(0);   // keep halves separate
    }
}

// ---------------------------------------------------------------------------
__device__ inline bool detect_int64(const int* e32) {
    int orv = 0;
#pragma unroll
    for (int k = 0; k < 8; k++) orv |= e32[2 * k + 1];
    return orv == 0;
}

// ---------------------------------------------------------------------------
// Kernel 2: quarter-wave per edge, permuted W2, 32 edges per wave-iteration
// (16 outstanding gathers per lane). 600000 % 32 == 0 -> no tail guard.
// ---------------------------------------------------------------------------
__global__ __launch_bounds__(256) void edge_mlp(
    const __half* __restrict__ P,
    const void* __restrict__ eidx_raw,
    const float* __restrict__ W2,
    const float* __restrict__ b2,
    float* __restrict__ out)
{
    const int* e32 = (const int*)eidx_raw;
    const long long* e64 = (const long long*)eidx_raw;
    const bool is64 = detect_int64(e32);

    const int tid  = threadIdx.x;
    const int lane = tid & 63;
    const int j    = lane & 15;
    const int grp  = lane >> 4;
    const int hbase = ((j >> 3) << 5) + ((j & 1) << 4) + (((j >> 1) & 3) << 2);
    const float4 w2 = *(const float4*)(W2 + hbase);
    const float b2v = b2[0];

    const int gwid   = (int)((blockIdx.x * blockDim.x + tid) >> 6);
    const int nwaves = (int)((gridDim.x * blockDim.x) >> 6);

    const half4v zero = {(_Float16)0, (_Float16)0, (_Float16)0, (_Float16)0};

    for (int base = gwid * 32; base < N_EDGES; base += nwaves * 32) {
        int s[8], d[8];
#pragma unroll
        for (int u = 0; u < 8; u++) {
            const int e = base + 4 * u + grp;
            if (is64) { s[u] = (int)e64[e]; d[u] = (int)e64[N_EDGES + e]; }
            else      { s[u] = e32[e];      d[u] = e32[N_EDGES + e]; }
        }
        half4v av[8], bv[8];
#pragma unroll
        for (int u = 0; u < 8; u++) {
            av[u] = *(const half4v*)(P + (size_t)s[u] * 128 + 4 * j);
            bv[u] = *(const half4v*)(P + (size_t)d[u] * 128 + 64 + 4 * j);
        }
#pragma unroll
        for (int u = 0; u < 8; u++) {
            const half4v t = av[u] + bv[u];
            const half4v r = __builtin_elementwise_max(t, zero);
            float acc = (float)r[0] * w2.x + (float)r[1] * w2.y
                      + (float)r[2] * w2.z + (float)r[3] * w2.w;
#pragma unroll
            for (int off = 8; off >= 1; off >>= 1)
                acc += __shfl_xor(acc, off, 64);
            if (j == 0) out[base + 4 * u + grp] = acc + b2v;
        }
    }
}

// ---------------------------------------------------------------------------
// Fallback (ws too small): direct per-edge compute, slow but correct.
// ---------------------------------------------------------------------------
__global__ __launch_bounds__(256) void edge_mlp_direct(
    const float* __restrict__ node_emb,
    const void* __restrict__ eidx_raw,
    const float* __restrict__ W1,
    const float* __restrict__ b1,
    const float* __restrict__ W2,
    const float* __restrict__ b2,
    float* __restrict__ out)
{
    const int* e32 = (const int*)eidx_raw;
    const long long* e64 = (const long long*)eidx_raw;
    const bool is64 = detect_int64(e32);

    const int lane = threadIdx.x & 63;
    const float w2  = W2[lane];
    const float b2v = b2[0];
    const int gwid   = (int)((blockIdx.x * blockDim.x + threadIdx.x) >> 6);
    const int nwaves = (int)((gridDim.x * blockDim.x) >> 6);

    for (int e = gwid; e < N_EDGES; e += nwaves) {
        int s, d;
        if (is64) { s = (int)e64[e]; d = (int)e64[N_EDGES + e]; }
        else      { s = e32[e];      d = e32[N_EDGES + e]; }
        const float* es = node_emb + (size_t)s * DIM;
        const float* ed = node_emb + (size_t)d * DIM;
        float acc = b1[lane];
        for (int k = 0; k < DIM; k++) {
            acc += es[k] * W1[k * HID + lane];
            acc += ed[k] * W1[(DIM + k) * HID + lane];
        }
        float t = fmaxf(acc, 0.f) * w2;
#pragma unroll
        for (int off = 32; off >= 1; off >>= 1)
            t += __shfl_xor(t, off, 64);
        if (lane == 0) out[e] = t + b2v;
    }
}

// ---------------------------------------------------------------------------
extern "C" void kernel_launch(void* const* d_in, const int* in_sizes, int n_in,
                              void* d_out, int out_size, void* d_ws, size_t ws_size,
                              hipStream_t stream) {
    const float* node_emb = (const float*)d_in[0];
    const void*  eidx     = d_in[1];
    const float* W1       = (const float*)d_in[2];
    const float* b1       = (const float*)d_in[3];
    const float* W2       = (const float*)d_in[4];
    const float* b2       = (const float*)d_in[5];
    float* out = (float*)d_out;

    const size_t wt_off = 32u * 1024 * 1024;
    const size_t need   = wt_off + 128 * 128 * sizeof(__half);

    if (ws_size >= need) {
        __half* P   = (__half*)d_ws;
        __half* W1T = (__half*)((char*)d_ws + wt_off);
        prep_W<<<32, 256, 0, stream>>>(W1, W1T);
        precompute_P<<<NCHUNK, 256, 0, stream>>>(node_emb, W1T, b1, P);
        edge_mlp<<<2048, 256, 0, stream>>>(P, eidx, W2, b2, out);
    } else {
        edge_mlp_direct<<<4096, 256, 0, stream>>>(node_emb, eidx, W1, b1, W2, b2, out);
    }
}